// Round 2
// baseline (453.191 us; speedup 1.0000x reference)
//
#include <hip/hip_runtime.h>

// VQEmbedding: B=32, T=1024, D=256, K=1024. N = 32768 rows.
// idx = argmin_k fl32( fl32(csqr_k + xsqr_i) - fl32(2*dot_ik) )   <- EMULATES the
// numpy/jax fp32 pipeline: adding xsqr~256 quantizes scores to ulp(256)~3e-5,
// creating ties resolved by FIRST INDEX. ~0.5% of rows are decided by this
// quantization, so we must reproduce it (round-1 lesson: argmin(csqr-2dot)
// without the +xsqr rounding mismatched ~80 rows).
// Then gather c_idx twice (z_q_x, z_q_x_bar) + write idx (as float) at 2*N*D.

#define NROWS   32768
#define DDIM    256
#define KCODES  1024
#define BLK     256
#define ROWS_PB 64     // rows per block (one per lane; 4 waves split the codes)
#define QC      256    // codes per wave (KCODES / 4 waves)
#define SUB     16     // codes per register subchunk

// --- kernel 1: csqr[k] = sum_d c[k][d]^2  (one wave per code) ---
__global__ __launch_bounds__(BLK) void vq_csqr_kernel(const float* __restrict__ cb,
                                                      float* __restrict__ csqr) {
    int gid  = blockIdx.x * BLK + threadIdx.x;
    int w    = gid >> 6;          // code index
    int lane = threadIdx.x & 63;
    if (w >= KCODES) return;
    float4 v = reinterpret_cast<const float4*>(cb)[w * (DDIM / 4) + lane];
    float s = v.x * v.x + v.y * v.y + v.z * v.z + v.w * v.w;
    #pragma unroll
    for (int off = 32; off > 0; off >>= 1) s += __shfl_down(s, off, 64);
    if (lane == 0) csqr[w] = s;
}

// --- kernel 2: main VQ ---
__global__ __launch_bounds__(BLK, 2) void vq_main_kernel(const float* __restrict__ x,
                                                         const float* __restrict__ cb,
                                                         const float* __restrict__ csqr,
                                                         float* __restrict__ out) {
    __shared__ float xl[ROWS_PB][DDIM + 1];   // pad 257: read bank = (lane+d)%32, conflict-free
    __shared__ float redv[4 * 64];
    __shared__ int   redi[4 * 64];
    __shared__ int   fidx[ROWS_PB];

    const int t  = threadIdx.x;
    const int r0 = blockIdx.x * ROWS_PB;

    // stage x tile: 64 rows x 256 f32, coalesced float4 reads
    for (int i = t; i < ROWS_PB * (DDIM / 4); i += BLK) {
        int row = i >> 6;          // 64 float4 per row
        int c4  = i & 63;
        float4 v = reinterpret_cast<const float4*>(x)[(size_t)(r0 + row) * (DDIM / 4) + c4];
        xl[row][c4 * 4 + 0] = v.x;
        xl[row][c4 * 4 + 1] = v.y;
        xl[row][c4 * 4 + 2] = v.z;
        xl[row][c4 * 4 + 3] = v.w;
    }
    __syncthreads();

    const int lane = t & 63;
    const int wq   = __builtin_amdgcn_readfirstlane(t >> 6);   // wave id 0..3, forced SGPR
    const float* xr = &xl[lane][0];

    // per-row ||x||^2, double-accumulated then rounded to fp32.
    // (absolute accuracy of xsqr only shifts all scores of the row uniformly;
    // what matters is that the +xsqr fp32 ADD below reproduces the grid.)
    double xs = 0.0;
    for (int d = 0; d < DDIM; ++d) {
        float v = xr[d];
        xs = fma((double)v, (double)v, xs);
    }
    const float xsq = (float)xs;

    float best = __builtin_inff();
    int   bi   = 0;

    for (int s = 0; s < QC / SUB; ++s) {
        const int code0 = wq * QC + s * SUB;   // wave-uniform
        float accL[SUB], accH[SUB];
        #pragma unroll
        for (int c = 0; c < SUB; ++c) { accL[c] = 0.f; accH[c] = 0.f; }

        // first half of D -> accL
        #pragma unroll 2
        for (int d = 0; d < DDIM / 2; d += 4) {
            float x0 = xr[d + 0], x1 = xr[d + 1], x2 = xr[d + 2], x3 = xr[d + 3];
            #pragma unroll
            for (int c = 0; c < SUB; ++c) {
                float4 cv = reinterpret_cast<const float4*>(cb)[(size_t)(code0 + c) * (DDIM / 4) + (d >> 2)];
                accL[c] = __fmaf_rn(x0, cv.x, accL[c]);
                accL[c] = __fmaf_rn(x1, cv.y, accL[c]);
                accL[c] = __fmaf_rn(x2, cv.z, accL[c]);
                accL[c] = __fmaf_rn(x3, cv.w, accL[c]);
            }
        }
        // second half of D -> accH
        #pragma unroll 2
        for (int d = DDIM / 2; d < DDIM; d += 4) {
            float x0 = xr[d + 0], x1 = xr[d + 1], x2 = xr[d + 2], x3 = xr[d + 3];
            #pragma unroll
            for (int c = 0; c < SUB; ++c) {
                float4 cv = reinterpret_cast<const float4*>(cb)[(size_t)(code0 + c) * (DDIM / 4) + (d >> 2)];
                accH[c] = __fmaf_rn(x0, cv.x, accH[c]);
                accH[c] = __fmaf_rn(x1, cv.y, accH[c]);
                accH[c] = __fmaf_rn(x2, cv.z, accH[c]);
                accH[c] = __fmaf_rn(x3, cv.w, accH[c]);
            }
        }
        // score in the reference's fp32 form: fl(fl(csqr + xsqr) - 2*dot)
        // (code ascending -> strict < gives first-index tie-break on the
        //  QUANTIZED values, matching np.argmin over the fp32 dist array)
        #pragma unroll
        for (int c = 0; c < SUB; ++c) {
            float dot   = __fadd_rn(accL[c], accH[c]);
            float tq    = __fadd_rn(csqr[code0 + c], xsq);   // uniform -> s_load
            float score = __fmaf_rn(-2.f, dot, tq);
            if (score < best) { best = score; bi = code0 + c; }
        }
    }

    redv[wq * 64 + lane] = best;
    redi[wq * 64 + lane] = bi;
    __syncthreads();

    if (t < 64) {
        float bv = redv[t];
        int   b  = redi[t];
        #pragma unroll
        for (int w = 1; w < 4; ++w) {
            float v  = redv[w * 64 + t];
            int   i2 = redi[w * 64 + t];
            if (v < bv) { bv = v; b = i2; }   // strict: lower wave = lower codes wins ties
        }
        fidx[t] = b;
        out[(size_t)2 * NROWS * DDIM + (r0 + t)] = (float)b;   // idx as float
    }
    __syncthreads();

    // gather winning code rows into out0 and out1, coalesced float4
    float4*       out0 = reinterpret_cast<float4*>(out);
    float4*       out1 = out0 + (size_t)NROWS * (DDIM / 4);
    const float4* cb4  = reinterpret_cast<const float4*>(cb);
    for (int i = t; i < ROWS_PB * (DDIM / 4); i += BLK) {
        int row = i >> 6;
        int c4  = i & 63;
        float4 v = cb4[(size_t)fidx[row] * (DDIM / 4) + c4];
        out0[(size_t)(r0 + row) * (DDIM / 4) + c4] = v;
        out1[(size_t)(r0 + row) * (DDIM / 4) + c4] = v;
    }
}

extern "C" void kernel_launch(void* const* d_in, const int* in_sizes, int n_in,
                              void* d_out, int out_size, void* d_ws, size_t ws_size,
                              hipStream_t stream) {
    const float* x   = (const float*)d_in[0];   // z_e_x  [32768, 256]
    const float* cb  = (const float*)d_in[1];   // codebook [1024, 256]
    float*       out = (float*)d_out;
    float*       ws  = (float*)d_ws;            // csqr[1024]

    vq_csqr_kernel<<<(KCODES * 64) / BLK, BLK, 0, stream>>>(cb, ws);
    vq_main_kernel<<<NROWS / ROWS_PB, BLK, 0, stream>>>(x, cb, ws, out);
}

// Round 3
// 242.935 us; speedup vs baseline: 1.8655x; 1.8655x over previous
//
#include <hip/hip_runtime.h>

// VQEmbedding: B=32,T=1024,D=256,K=1024. N=32768 rows.
// idx = argmin_k fl32( fl32(csqr_k + xsqr_i) - 2*dot_ik )  (fp32-grid emulation, proven r2).
// Grid-shift invariance: any fp32 xsqr near 256 differs from the reference's by an exact
// multiple of the score grid ulp -> all quantized scores shift uniformly -> argmin invariant.
// So xsqr is computed in plain fp32 (no fp64 needed).
//
// Round-3 structure: cbt[d][k] transposed codebook; lane owns 2 codes; 8 waves x 128 = all
// 1024 codes per block; block reduces 16 rows. x loads are wave-uniform -> s_load (scalar
// pipe); code loads coalesced float2 (1 VMEM per 32 FMA). Dot chains bit-identical to r2
// (two 128-FMA halves + one add). Argmin: packed u64 (score_bits<<32)|idx, butterfly +
// LDS cross-wave min; gather fused.

#define NROWS  32768
#define DDIM   256
#define KCODES 1024
#define RG     16    // rows per block
#define WAVES  8
#define BLKM   512

// --- csqr[k] = sum_d cb[k][d]^2 (one wave per code) — unchanged from r2 (passed) ---
__global__ __launch_bounds__(256) void vq_csqr(const float* __restrict__ cb,
                                               float* __restrict__ csqr) {
    int gid  = blockIdx.x * 256 + threadIdx.x;
    int w    = gid >> 6;
    int lane = threadIdx.x & 63;
    if (w >= KCODES) return;
    float4 v = reinterpret_cast<const float4*>(cb)[w * (DDIM / 4) + lane];
    float s = v.x * v.x + v.y * v.y + v.z * v.z + v.w * v.w;
    #pragma unroll
    for (int off = 32; off > 0; off >>= 1) s += __shfl_down(s, off, 64);
    if (lane == 0) csqr[w] = s;
}

// --- xsqr[r] = sum_d x[r][d]^2, fp32 (order-invariant by grid-shift argument) ---
__global__ __launch_bounds__(256) void vq_xsqr(const float* __restrict__ x,
                                               float* __restrict__ xsqr) {
    int w = threadIdx.x >> 6, lane = threadIdx.x & 63;
    int row = blockIdx.x * 4 + w;
    float4 v = reinterpret_cast<const float4*>(x + (size_t)row * DDIM)[lane];
    float s = v.x * v.x + v.y * v.y + v.z * v.z + v.w * v.w;
    #pragma unroll
    for (int off = 32; off > 0; off >>= 1) s += __shfl_down(s, off, 64);
    if (lane == 0) xsqr[row] = s;
}

// --- transpose cb[1024][256] -> cbt[256][1024] (LDS 64x64 tile, padded) ---
__global__ __launch_bounds__(256) void vq_tr(const float* __restrict__ cb,
                                             float* __restrict__ cbt) {
    __shared__ float tile[64][65];
    int k0 = (blockIdx.x >> 2) * 64;   // 16 code tiles
    int d0 = (blockIdx.x & 3) * 64;    // 4 dim tiles
    int c  = threadIdx.x & 63;
    int r4 = threadIdx.x >> 6;         // 0..3
    #pragma unroll
    for (int i = 0; i < 16; ++i) {
        int r = i * 4 + r4;
        tile[r][c] = cb[(size_t)(k0 + r) * DDIM + d0 + c];
    }
    __syncthreads();
    #pragma unroll
    for (int i = 0; i < 16; ++i) {
        int r = i * 4 + r4;
        cbt[(size_t)(d0 + r) * KCODES + k0 + c] = tile[c][r];   // bank (c+r)%32: clean
    }
}

// --- main: 16 rows/block, all 1024 codes, fused argmin + gather ---
__device__ __forceinline__ void body4(const float* __restrict__ xb,
                                      const float* __restrict__ cbp,
                                      int d4, float (&a0)[RG], float (&a1)[RG]) {
    const float* cd = cbp + (size_t)d4 * 4 * KCODES;
    float2 cv0 = *(const float2*)(cd);
    float2 cv1 = *(const float2*)(cd + KCODES);
    float2 cv2 = *(const float2*)(cd + 2 * KCODES);
    float2 cv3 = *(const float2*)(cd + 3 * KCODES);
    #pragma unroll
    for (int r = 0; r < RG; ++r) {
        float4 xv = *(const float4*)(xb + r * DDIM + d4 * 4);   // uniform -> s_load_dwordx4
        a0[r] = __fmaf_rn(xv.x, cv0.x, a0[r]);
        a1[r] = __fmaf_rn(xv.x, cv0.y, a1[r]);
        a0[r] = __fmaf_rn(xv.y, cv1.x, a0[r]);
        a1[r] = __fmaf_rn(xv.y, cv1.y, a1[r]);
        a0[r] = __fmaf_rn(xv.z, cv2.x, a0[r]);
        a1[r] = __fmaf_rn(xv.z, cv2.y, a1[r]);
        a0[r] = __fmaf_rn(xv.w, cv3.x, a0[r]);
        a1[r] = __fmaf_rn(xv.w, cv3.y, a1[r]);
    }
}

__global__ __launch_bounds__(BLKM, 4) void vq_main(const float* __restrict__ x,
                                                   const float* __restrict__ cbt,
                                                   const float* __restrict__ csqr,
                                                   const float* __restrict__ xsqr,
                                                   const float* __restrict__ cb,
                                                   float* __restrict__ out) {
    __shared__ unsigned long long kred[WAVES][RG];
    __shared__ int fidx[RG];

    const int t    = threadIdx.x;
    const int lane = t & 63;
    const int w    = __builtin_amdgcn_readfirstlane(t >> 6);   // 0..7
    const int r0   = blockIdx.x * RG;

    const int    code0 = w * 128 + lane * 2;     // lane owns (code0, code0+1)
    const float* cbp   = cbt + code0;
    const float* xb    = x + (size_t)r0 * DDIM;

    float accA0[RG], accA1[RG], accB0[RG], accB1[RG];
    #pragma unroll
    for (int r = 0; r < RG; ++r) { accA0[r] = 0.f; accA1[r] = 0.f; accB0[r] = 0.f; accB1[r] = 0.f; }

    #pragma unroll 2
    for (int d4 = 0; d4 < 32; ++d4)  body4(xb, cbp, d4, accA0, accA1);   // d 0..127
    #pragma unroll 2
    for (int d4 = 32; d4 < 64; ++d4) body4(xb, cbp, d4, accB0, accB1);   // d 128..255

    const float csq0 = csqr[code0];
    const float csq1 = csqr[code0 + 1];

    unsigned long long myk = ~0ULL;
    #pragma unroll
    for (int r = 0; r < RG; ++r) {
        float xsq = xsqr[r0 + r];                               // uniform -> s_load
        float d0  = __fadd_rn(accA0[r], accB0[r]);              // bit-identical to r2 chains
        float d1  = __fadd_rn(accA1[r], accB1[r]);
        float s0  = __fmaf_rn(-2.f, d0, __fadd_rn(csq0, xsq));  // fl(tq - 2dot), single rnd
        float s1  = __fmaf_rn(-2.f, d1, __fadd_rn(csq1, xsq));
        unsigned long long k0 = ((unsigned long long)__float_as_uint(s0) << 32) | (unsigned)code0;
        unsigned long long k1 = ((unsigned long long)__float_as_uint(s1) << 32) | (unsigned)(code0 + 1);
        unsigned long long kk = k0 < k1 ? k0 : k1;              // scores>0: bit order = float order
        #pragma unroll
        for (int m = 1; m < 64; m <<= 1) {
            unsigned long long o = __shfl_xor(kk, m, 64);
            kk = o < kk ? o : kk;
        }
        myk = (lane == r) ? kk : myk;                           // static idx only (rule #20)
    }
    if (lane < RG) kred[w][lane] = myk;
    __syncthreads();

    if (t < RG) {
        unsigned long long b = kred[0][t];
        #pragma unroll
        for (int ww = 1; ww < WAVES; ++ww) {
            unsigned long long v = kred[ww][t];
            b = v < b ? v : b;
        }
        int bi = (int)(unsigned)(b & 0xffffffffu);
        fidx[t] = bi;
        out[(size_t)2 * NROWS * DDIM + (r0 + t)] = (float)bi;   // idx as float
    }
    __syncthreads();

    // fused gather: 16 rows x 64 float4-cols = 1024 items, 512 threads x 2
    const float4* cb4  = (const float4*)cb;
    float4*       out0 = (float4*)out;
    float4*       out1 = out0 + (size_t)NROWS * (DDIM / 4);
    #pragma unroll
    for (int i = 0; i < (RG * 64) / BLKM; ++i) {
        int it  = i * BLKM + t;
        int row = it >> 6, col = it & 63;
        float4 v = cb4[(size_t)fidx[row] * (DDIM / 4) + col];
        size_t o = (size_t)(r0 + row) * (DDIM / 4) + col;
        out0[o] = v;
        out1[o] = v;
    }
}

extern "C" void kernel_launch(void* const* d_in, const int* in_sizes, int n_in,
                              void* d_out, int out_size, void* d_ws, size_t ws_size,
                              hipStream_t stream) {
    const float* x   = (const float*)d_in[0];   // z_e_x   [32768,256]
    const float* cb  = (const float*)d_in[1];   // codebook [1024,256]
    float*       out = (float*)d_out;

    float* ws_cbt  = (float*)d_ws;              // [256][1024] transposed codebook
    float* ws_csqr = ws_cbt + DDIM * KCODES;    // [1024]
    float* ws_xsqr = ws_csqr + KCODES;          // [32768]

    vq_tr  <<<64,                    256, 0, stream>>>(cb, ws_cbt);
    vq_csqr<<<(KCODES * 64) / 256,   256, 0, stream>>>(cb, ws_csqr);
    vq_xsqr<<<NROWS / 4,             256, 0, stream>>>(x, ws_xsqr);
    vq_main<<<NROWS / RG,           BLKM, 0, stream>>>(x, ws_cbt, ws_csqr, ws_xsqr, cb, out);
}

// Round 4
// 230.231 us; speedup vs baseline: 1.9684x; 1.0552x over previous
//
#include <hip/hip_runtime.h>

// VQEmbedding: B=32,T=1024,D=256,K=1024. N=32768 rows.
// Exact score (proven r2/r3): s = fl32( fl32(csqr_k + xsqr_i) - 2*dot_ik ), argmin with
// first-index ties. Round 4: bf16 MFMA computes APPROX dots; codes within MARGIN of each
// row-subset's approx-min are exactly rescored with the r3-proven fp32 chain + grid
// formula; packed-u64 atomicMin gives min-score-then-min-index. A built-in self-check
// (16 codes x 128 rows vs exact) triggers a full exact brute-force fallback if the MFMA
// fragment-layout assumption is wrong -> correctness is layout-independent.

#define NROWS  32768
#define DDIM   256
#define KCODES 1024
#define MARGIN 1.5e-3f
#define CHKTHR 2.5e-3f
#define CAP    2048

typedef __attribute__((ext_vector_type(8))) short short8;
typedef __attribute__((ext_vector_type(4))) float f32x4;

__device__ __forceinline__ unsigned short f2bf(float f) {   // RNE f32->bf16 (no NaN inputs)
    unsigned u = __float_as_uint(f);
    return (unsigned short)((u + 0x7FFFu + ((u >> 16) & 1u)) >> 16);
}

// exact fp32 dot, chain structure bit-identical to the r3-proven kernel:
// chain A = d 0..127, chain B = d 128..255, sequential x/y/z/w FMAs, one final add.
__device__ __forceinline__ float exact_dot(const float* __restrict__ xrow,
                                           const float* __restrict__ crow) {
    const float4* xp = (const float4*)xrow;
    const float4* cp = (const float4*)crow;
    float A = 0.f, B = 0.f;
    #pragma unroll 8
    for (int d4 = 0; d4 < 32; ++d4) {
        float4 xv = xp[d4], cv = cp[d4];
        A = __fmaf_rn(xv.x, cv.x, A);
        A = __fmaf_rn(xv.y, cv.y, A);
        A = __fmaf_rn(xv.z, cv.z, A);
        A = __fmaf_rn(xv.w, cv.w, A);
    }
    #pragma unroll 8
    for (int d4 = 32; d4 < 64; ++d4) {
        float4 xv = xp[d4], cv = cp[d4];
        B = __fmaf_rn(xv.x, cv.x, B);
        B = __fmaf_rn(xv.y, cv.y, B);
        B = __fmaf_rn(xv.z, cv.z, B);
        B = __fmaf_rn(xv.w, cv.w, B);
    }
    return __fadd_rn(A, B);
}

// --- csqr[k] = sum_d cb[k][d]^2 (proven r3) ---
__global__ __launch_bounds__(256) void vq_csqr(const float* __restrict__ cb,
                                               float* __restrict__ csqr) {
    int gid  = blockIdx.x * 256 + threadIdx.x;
    int w    = gid >> 6;
    int lane = threadIdx.x & 63;
    if (w >= KCODES) return;
    float4 v = reinterpret_cast<const float4*>(cb)[w * (DDIM / 4) + lane];
    float s = v.x * v.x + v.y * v.y + v.z * v.z + v.w * v.w;
    #pragma unroll
    for (int off = 32; off > 0; off >>= 1) s += __shfl_down(s, off, 64);
    if (lane == 0) csqr[w] = s;
}

// --- xsqr[r] = sum_d x[r][d]^2 (proven r3; fp32 OK by grid-shift invariance) ---
__global__ __launch_bounds__(256) void vq_xsqr(const float* __restrict__ x,
                                               float* __restrict__ xsqr) {
    int w = threadIdx.x >> 6, lane = threadIdx.x & 63;
    int row = blockIdx.x * 4 + w;
    float4 v = reinterpret_cast<const float4*>(x + (size_t)row * DDIM)[lane];
    float s = v.x * v.x + v.y * v.y + v.z * v.z + v.w * v.w;
    #pragma unroll
    for (int off = 32; off > 0; off >>= 1) s += __shfl_down(s, off, 64);
    if (lane == 0) xsqr[row] = s;
}

// --- cb f32 -> bf16 in B-fragment order: frag(nt,ks): lane l, elem i holds
//     cb[nt*16 + (l&15)][ks*32 + (l>>4)*8 + i].  Linear id = (nt*8+ks)*64 + l. ---
__global__ __launch_bounds__(256) void vq_cbfrag(const float* __restrict__ cb,
                                                 short* __restrict__ cbh) {
    int id   = blockIdx.x * 256 + threadIdx.x;   // 0..32767
    int lane = id & 63;
    int ks   = (id >> 6) & 7;
    int nt   = id >> 9;                          // 0..63
    int code = nt * 16 + (lane & 15);
    int d0   = ks * 32 + (lane >> 4) * 8;
    const float4* p = (const float4*)(cb + (size_t)code * DDIM + d0);
    float4 a = p[0], b = p[1];
    short8 v;
    v[0] = (short)f2bf(a.x); v[1] = (short)f2bf(a.y);
    v[2] = (short)f2bf(a.z); v[3] = (short)f2bf(a.w);
    v[4] = (short)f2bf(b.x); v[5] = (short)f2bf(b.y);
    v[6] = (short)f2bf(b.z); v[7] = (short)f2bf(b.w);
    *(short8*)(cbh + (size_t)id * 8) = v;
}

// --- main: 128 rows/block, 8 waves = (mtp 0..3) x (q 0..1); A-frags in regs,
//     B coalesced from cbh (L2); approx scores -> margin candidates -> exact rescore. ---
__global__ __launch_bounds__(512, 2) void vq_main(const float* __restrict__ x,
                                                  const float* __restrict__ cb,
                                                  const short* __restrict__ cbh,
                                                  const float* __restrict__ csqr,
                                                  const float* __restrict__ xsqr,
                                                  float* __restrict__ out) {
    __shared__ float              csl[KCODES];
    __shared__ unsigned long long keys[128];
    __shared__ float              chk[128][16];
    __shared__ unsigned           list[CAP];
    __shared__ int                fidx[128];
    __shared__ int                cnt, bad;

    const int t    = threadIdx.x;
    const int lane = t & 63;
    const int w    = t >> 6;          // 0..7
    const int mtp  = w >> 1;          // 0..3 (row pair)
    const int q    = w & 1;           // 0..1 (code half)
    const int r0   = blockIdx.x * 128;
    const int lr   = lane & 15;       // fragment row/col index
    const int lg   = lane >> 4;       // fragment k-group

    // stage csqr -> LDS; init reduction state
    if (t < 256) ((float4*)csl)[t] = ((const float4*)csqr)[t];
    if (t < 128) keys[t] = ~0ULL;
    if (t == 0) { cnt = 0; bad = 0; }

    // A-fragments (bf16 x rows), held across all chunks.
    // afr[mt][ks]: lane l elem i = x[rowbase(mt)+ (l&15)][ks*32 + (l>>4)*8 + i]
    short8 afr[2][8];
    #pragma unroll
    for (int mt = 0; mt < 2; ++mt) {
        int row = r0 + mtp * 32 + mt * 16 + lr;
        #pragma unroll
        for (int ks = 0; ks < 8; ++ks) {
            const float4* p = (const float4*)(x + (size_t)row * DDIM + ks * 32 + lg * 8);
            float4 a = p[0], b = p[1];
            short8 v;
            v[0] = (short)f2bf(a.x); v[1] = (short)f2bf(a.y);
            v[2] = (short)f2bf(a.z); v[3] = (short)f2bf(a.w);
            v[4] = (short)f2bf(b.x); v[5] = (short)f2bf(b.y);
            v[6] = (short)f2bf(b.z); v[7] = (short)f2bf(b.w);
            afr[mt][ks] = v;
        }
    }
    __syncthreads();

    float runm[2][4];
    #pragma unroll
    for (int mt = 0; mt < 2; ++mt)
        #pragma unroll
        for (int j = 0; j < 4; ++j) runm[mt][j] = __builtin_inff();

    for (int c = 0; c < 4; ++c) {               // 4 chunks of 256 codes
        f32x4 af[2][8];
        #pragma unroll
        for (int mt = 0; mt < 2; ++mt)
            #pragma unroll
            for (int n = 0; n < 8; ++n) af[mt][n] = (f32x4){0.f, 0.f, 0.f, 0.f};

        #pragma unroll
        for (int ks = 0; ks < 8; ++ks) {
            short8 bv[8];
            #pragma unroll
            for (int n = 0; n < 8; ++n) {
                int nt = c * 16 + q * 8 + n;
                bv[n] = *(const short8*)(cbh + (size_t)((nt * 8 + ks) * 64 + lane) * 8);
            }
            #pragma unroll
            for (int n = 0; n < 8; ++n) {
                af[0][n] = __builtin_amdgcn_mfma_f32_16x16x32_bf16(afr[0][ks], bv[n], af[0][n], 0, 0, 0);
                af[1][n] = __builtin_amdgcn_mfma_f32_16x16x32_bf16(afr[1][ks], bv[n], af[1][n], 0, 0, 0);
            }
        }

        // ---- epilogue: C/D layout col=lane&15, row=(lane>>4)*4+j (verified m89) ----
        const int cbase = c * 256 + q * 128 + lr;   // + n*16
        float m[2][4];
        #pragma unroll
        for (int mt = 0; mt < 2; ++mt) {
            #pragma unroll
            for (int j = 0; j < 4; ++j) m[mt][j] = __builtin_inff();
            #pragma unroll
            for (int n = 0; n < 8; ++n) {
                float cs1 = __fadd_rn(csl[cbase + n * 16], 1.0f);   // +1: keep score>0 (bit order)
                #pragma unroll
                for (int j = 0; j < 4; ++j) {
                    float s = __fmaf_rn(-2.f, af[mt][n][j], cs1);
                    m[mt][j] = fminf(m[mt][j], s);
                }
            }
        }
        #pragma unroll
        for (int mt = 0; mt < 2; ++mt)
            #pragma unroll
            for (int j = 0; j < 4; ++j) {
                float v = m[mt][j];
                v = fminf(v, __shfl_xor(v, 1, 64));
                v = fminf(v, __shfl_xor(v, 2, 64));
                v = fminf(v, __shfl_xor(v, 4, 64));
                v = fminf(v, __shfl_xor(v, 8, 64));
                runm[mt][j] = fminf(runm[mt][j], v);
            }
        // candidates (winner guaranteed: s(win) <= runmin + 2*apx_err <= runmin + MARGIN)
        #pragma unroll
        for (int mt = 0; mt < 2; ++mt) {
            #pragma unroll
            for (int n = 0; n < 8; ++n) {
                float cs1 = __fadd_rn(csl[cbase + n * 16], 1.0f);
                #pragma unroll
                for (int j = 0; j < 4; ++j) {
                    float s    = __fmaf_rn(-2.f, af[mt][n][j], cs1);
                    int   rloc = mtp * 32 + mt * 16 + lg * 4 + j;
                    if (c == 0 && q == 0 && n == 0) chk[rloc][lr] = s;   // self-check ref
                    if (s <= runm[mt][j] + MARGIN) {
                        int pos = atomicAdd(&cnt, 1);
                        if (pos < CAP) list[pos] = ((unsigned)rloc << 16) | (unsigned)(cbase + n * 16);
                        else bad = 1;
                    }
                }
            }
        }
    }
    __syncthreads();

    // ---- self-check: exact vs MFMA on codes 0..15 for all 128 rows ----
    #pragma unroll
    for (int p = 0; p < 4; ++p) {
        int id   = t + p * 512;          // 0..2047
        int rloc = id >> 4, cc = id & 15;
        float dot = exact_dot(x + (size_t)(r0 + rloc) * DDIM, cb + (size_t)cc * DDIM);
        float ex  = __fmaf_rn(-2.f, dot, __fadd_rn(csl[cc], 1.0f));
        if (fabsf(ex - chk[rloc][cc]) > CHKTHR) bad = 1;
    }
    __syncthreads();

    if (bad || cnt > CAP) {
        // fallback: exact brute force over all codes (layout-independent correctness)
        for (int it = t; it < 128 * KCODES; it += 512) {
            int rloc = it >> 10, code = it & (KCODES - 1);
            float dot = exact_dot(x + (size_t)(r0 + rloc) * DDIM, cb + (size_t)code * DDIM);
            float s   = __fmaf_rn(-2.f, dot, __fadd_rn(csl[code], xsqr[r0 + rloc]));
            unsigned long long key = ((unsigned long long)__float_as_uint(s) << 32) | (unsigned)code;
            atomicMin(&keys[rloc], key);
        }
    } else {
        for (int i = t; i < cnt; i += 512) {
            unsigned e  = list[i];
            int rloc    = (int)(e >> 16), code = (int)(e & 0xffffu);
            float dot = exact_dot(x + (size_t)(r0 + rloc) * DDIM, cb + (size_t)code * DDIM);
            float s   = __fmaf_rn(-2.f, dot, __fadd_rn(csl[code], xsqr[r0 + rloc]));   // r3-proven grid form
            unsigned long long key = ((unsigned long long)__float_as_uint(s) << 32) | (unsigned)code;
            atomicMin(&keys[rloc], key);
        }
    }
    __syncthreads();

    if (t < 128) {
        int code = (int)(unsigned)(keys[t] & 0xffffffffu);
        fidx[t] = code;
        out[(size_t)2 * NROWS * DDIM + (r0 + t)] = (float)code;
    }
    __syncthreads();

    const float4* cb4  = (const float4*)cb;
    float4*       out0 = (float4*)out;
    float4*       out1 = out0 + (size_t)NROWS * (DDIM / 4);
    #pragma unroll
    for (int i = 0; i < 16; ++i) {
        int it  = i * 512 + t;           // 128 rows x 64 float4
        int row = it >> 6, col = it & 63;
        float4 v = cb4[(size_t)fidx[row] * (DDIM / 4) + col];
        size_t o = (size_t)(r0 + row) * (DDIM / 4) + col;
        out0[o] = v;
        out1[o] = v;
    }
}

extern "C" void kernel_launch(void* const* d_in, const int* in_sizes, int n_in,
                              void* d_out, int out_size, void* d_ws, size_t ws_size,
                              hipStream_t stream) {
    const float* x   = (const float*)d_in[0];   // z_e_x   [32768,256]
    const float* cb  = (const float*)d_in[1];   // codebook [1024,256]
    float*       out = (float*)d_out;

    float* ws_csqr = (float*)d_ws;                    // [1024]
    float* ws_xsqr = ws_csqr + KCODES;                // [32768]
    short* ws_cbh  = (short*)(ws_xsqr + NROWS);       // [1024*256] bf16 frags (16B aligned)

    vq_cbfrag<<<128,  256, 0, stream>>>(cb, ws_cbh);
    vq_csqr  <<<256,  256, 0, stream>>>(cb, ws_csqr);
    vq_xsqr  <<<NROWS / 4, 256, 0, stream>>>(x, ws_xsqr);
    vq_main  <<<NROWS / 128, 512, 0, stream>>>(x, cb, ws_cbh, ws_csqr, ws_xsqr, out);
}